// Round 2
// baseline (308.694 us; speedup 1.0000x reference)
//
#include <hip/hip_runtime.h>
#include <hip/hip_bf16.h>

// Problem constants
#define T_DIM 8192
#define IN_DIM 1024
#define RES_DIM 4096

typedef unsigned short u16;
typedef __bf16 bf16x8 __attribute__((ext_vector_type(8)));
typedef float f32x4 __attribute__((ext_vector_type(4)));

// ---------- helpers ----------
__device__ __forceinline__ u16 f2bf(float f) {
    unsigned u = __float_as_uint(f);
    return (u16)((u + 0x7FFFu + ((u >> 16) & 1u)) >> 16);   // RNE
}
__device__ __forceinline__ float bf2f(u16 h) {
    return __uint_as_float(((unsigned)h) << 16);
}

__device__ __forceinline__ float tanh_fast(float z) {
    z = fminf(15.0f, fmaxf(-15.0f, z));
    float e = __expf(2.0f * z);
    float inv = __builtin_amdgcn_rcpf(e + 1.0f);
    return fmaf(-2.0f, inv, 1.0f);
}

__device__ __forceinline__ void stage16(const u16* g, u16* l) {
    __builtin_amdgcn_global_load_lds(
        (const __attribute__((address_space(1))) void*)g,
        (__attribute__((address_space(3))) void*)l, 16, 0, 0);
}

// ---------- convert: f32 row-major [rows][1024] -> tiled hi(kta 0..15)/lo(kta 16..31) bf16 ----------
// Tiled elem index: (((rb*32 + kta)*2 + h)*16 + fb)*64 + l, *8 + e
//   rb = row>>8, h = (row>>7)&1, fb = ((row>>4)&7)*2 + ks, l = kg*16 + (row&15)
//   k = kta_local*64 + ks*32 + kg*8 + e
__global__ void convert_hilo(const float* __restrict__ src, u16* __restrict__ dst, int nchunks) {
    for (int g = blockIdx.x * blockDim.x + threadIdx.x; g < nchunks;
         g += gridDim.x * blockDim.x) {
        int row = g >> 7, kc = g & 127;
        int rb = row >> 8, h = (row >> 7) & 1, mf = (row >> 4) & 7, r4 = row & 15;
        int kth = kc >> 3, ks = (kc >> 2) & 1, kg = kc & 3;
        int l = kg * 16 + r4, fb = mf * 2 + ks;
        const float* s = src + (size_t)row * IN_DIM + kc * 8;
        float4 f0 = *(const float4*)s;
        float4 f1 = *(const float4*)(s + 4);
        float f[8] = {f0.x, f0.y, f0.z, f0.w, f1.x, f1.y, f1.z, f1.w};
        alignas(16) u16 hv[8];
        alignas(16) u16 lv[8];
#pragma unroll
        for (int e = 0; e < 8; ++e) {
            u16 hh = f2bf(f[e]);
            hv[e] = hh;
            lv[e] = f2bf(f[e] - bf2f(hh));
        }
        size_t baseHi = ((((size_t)(rb * 32 + kth) * 2 + h) * 16 + fb) * 64 + l) * 8;
        size_t baseLo = ((((size_t)(rb * 32 + kth + 16) * 2 + h) * 16 + fb) * 64 + l) * 8;
        *(uint4*)(dst + baseHi) = *(const uint4*)hv;
        *(uint4*)(dst + baseLo) = *(const uint4*)lv;
    }
}

// ---------- 256x256 8-phase bf16 GEMM over K'=3072 (hi/lo 3-segment) ----------
// Segments: kt 0..15: Ah*Bh ; 16..31: Ah*Bl ; 32..47: Al*Bh
//   a_kta = kt<16 ? kt : kt-16  (Aop: [0..15]=hi, [16..31]=lo)
//   b_ktb = kt<32 ? kt : kt-32  (Bop: [0..15]=hi, [16..31]=lo)
#define FENCE() asm volatile("" ::: "memory")
#define BAR()   do { FENCE(); __builtin_amdgcn_s_barrier(); FENCE(); } while (0)
#define WAIT2() asm volatile("s_waitcnt vmcnt(2)" ::: "memory")
#define WAIT0() asm volatile("s_waitcnt vmcnt(0)" ::: "memory")

__global__ __launch_bounds__(512, 2)
void gemm8(const u16* __restrict__ Aop, const u16* __restrict__ Bop, float* __restrict__ C) {
    __shared__ __attribute__((aligned(16))) u16 sA[2][2][8192];
    __shared__ __attribute__((aligned(16))) u16 sB[2][2][8192];

    const int tid  = threadIdx.x;
    const int lane = tid & 63;
    const int w    = tid >> 6;
    const int wr = w >> 2, wc = w & 3;

    // bijective XCD swizzle (512 blocks, 512%8==0)
    const int bid = blockIdx.x;
    const int swz = (bid & 7) * 64 + (bid >> 3);
    const int mb = swz >> 4;   // 0..31
    const int nb = swz & 15;   // 0..15

    f32x4 acc[8][4] = {};
    bf16x8 aR[4][2], bR[2][2];

    const int wbase0 = (tid & ~63) * 8;   // wave-uniform LDS elem base

#define STAGE_A(kt, h, d) do { if ((kt) < 48) {                                    \
    int kta_ = ((kt) < 16) ? (kt) : ((kt) - 16);                                   \
    const u16* s_ = Aop + (size_t)((mb * 32 + kta_) * 2 + (h)) * 8192 + tid * 8;   \
    u16* l_ = &sA[d][h][0] + wbase0;                                               \
    stage16(s_, l_);                                                               \
    stage16(s_ + 4096, l_ + 4096); } } while (0)

#define STAGE_B(kt, h, d) do { if ((kt) < 48) {                                    \
    int ktb_ = ((kt) < 32) ? (kt) : ((kt) - 32);                                   \
    const u16* s_ = Bop + (size_t)((nb * 32 + ktb_) * 2 + (h)) * 8192 + tid * 8;   \
    u16* l_ = &sB[d][h][0] + wbase0;                                               \
    stage16(s_, l_);                                                               \
    stage16(s_ + 4096, l_ + 4096); } } while (0)

#define LOAD_A(d, mh) do {                                                          \
    _Pragma("unroll") for (int i_ = 0; i_ < 4; ++i_)                                \
    _Pragma("unroll") for (int ks_ = 0; ks_ < 2; ++ks_)                             \
        aR[i_][ks_] = *(const bf16x8*)(&sA[d][wr][0] +                              \
            (((mh) * 4 + i_) * 2 + ks_) * 512 + lane * 8); } while (0)

#define LOAD_B(d, nh) do {                                                          \
    _Pragma("unroll") for (int j_ = 0; j_ < 2; ++j_)                                \
    _Pragma("unroll") for (int ks_ = 0; ks_ < 2; ++ks_)                             \
        bR[j_][ks_] = *(const bf16x8*)(&sB[d][wc >> 1][0] +                         \
            (((wc & 1) * 4 + (nh) * 2 + j_) * 2 + ks_) * 512 + lane * 8); } while (0)

#define MFMA_Q(mh, nh) do {                                                         \
    __builtin_amdgcn_s_setprio(1);                                                  \
    _Pragma("unroll") for (int i_ = 0; i_ < 4; ++i_)                                \
    _Pragma("unroll") for (int j_ = 0; j_ < 2; ++j_) {                              \
        acc[(mh)*4+i_][(nh)*2+j_] = __builtin_amdgcn_mfma_f32_16x16x32_bf16(        \
            aR[i_][0], bR[j_][0], acc[(mh)*4+i_][(nh)*2+j_], 0, 0, 0);              \
        acc[(mh)*4+i_][(nh)*2+j_] = __builtin_amdgcn_mfma_f32_16x16x32_bf16(        \
            aR[i_][1], bR[j_][1], acc[(mh)*4+i_][(nh)*2+j_], 0, 0, 0); }            \
    __builtin_amdgcn_s_setprio(0); } while (0)

// One iteration = 2 K-tiles (dbuf 0 then 1), 8 phases.
// Stage schedule: p1-p3 -> kt+1 (A11,B10,B11), p4-p7 -> kt+2 (A00,A01,B00,B01), p8 -> kt+3 (A10).
// Waits at p4/p8 leave exactly the newest phase's 2 loads in flight.
#define ITER(kb, W4, W8)                                                            \
    LOAD_A(0, 0); LOAD_B(0, 0); STAGE_A((kb)+1, 1, 1); BAR(); MFMA_Q(0, 0); BAR();  \
    LOAD_B(0, 1);               STAGE_B((kb)+1, 0, 1); BAR(); MFMA_Q(0, 1); BAR();  \
    LOAD_A(0, 1);               STAGE_B((kb)+1, 1, 1); BAR(); MFMA_Q(1, 1); BAR();  \
    LOAD_B(0, 0);               STAGE_A((kb)+2, 0, 0); W4; BAR(); MFMA_Q(1, 0); BAR(); \
    LOAD_A(1, 0); LOAD_B(1, 0); STAGE_A((kb)+2, 1, 0); BAR(); MFMA_Q(0, 0); BAR();  \
    LOAD_B(1, 1);               STAGE_B((kb)+2, 0, 0); BAR(); MFMA_Q(0, 1); BAR();  \
    LOAD_A(1, 1);               STAGE_B((kb)+2, 1, 0); BAR(); MFMA_Q(1, 1); BAR();  \
    LOAD_B(1, 0);               STAGE_A((kb)+3, 0, 1); W8; BAR(); MFMA_Q(1, 0); BAR();

    // prologue: kt0 fully + kt1's A-h0; allow kt1's loads in flight
    STAGE_A(0, 0, 0); STAGE_A(0, 1, 0); STAGE_B(0, 0, 0); STAGE_B(0, 1, 0);
    STAGE_A(1, 0, 1);
    WAIT2(); BAR();

    for (int it = 0; it < 23; ++it) {
        const int kb = it * 2;
        ITER(kb, WAIT2(), WAIT2());
    }
    {   // tail iteration: kb=46; kt48/49 stages auto-skip; drain before reading kt47
        const int kb = 46;
        ITER(kb, WAIT0(), FENCE());
    }

    // epilogue: D layout col = lane&15, row = (lane>>4)*4 + j
    const int lr = lane & 15, lq = lane >> 4;
    const size_t row0 = (size_t)mb * 256 + wr * 128;
    const size_t col0 = (size_t)nb * 256 + wc * 64;
#pragma unroll
    for (int m = 0; m < 8; ++m)
#pragma unroll
        for (int n = 0; n < 4; ++n) {
            float* cp = C + (row0 + m * 16 + lq * 4) * RES_DIM + (col0 + n * 16 + lr);
#pragma unroll
            for (int j = 0; j < 4; ++j) cp[(size_t)j * RES_DIM] = acc[m][n][j];
        }
#undef ITER
#undef MFMA_Q
#undef LOAD_B
#undef LOAD_A
#undef STAGE_B
#undef STAGE_A
}

// ---------- fallback fp32 GEMM (only if ws too small) ----------
__global__ __launch_bounds__(256)
void gemm_f32(const float* __restrict__ A, const float* __restrict__ B, float* __restrict__ C) {
    __shared__ float sAf[64][33];
    __shared__ float sBf[64][33];
    const int tid = threadIdx.x;
    const int tx = tid & 15, ty = tid >> 4;
    const size_t t0 = (size_t)blockIdx.x * 64;
    const size_t r0 = (size_t)blockIdx.y * 64;
    const int lrow = tid >> 2;
    const int lcol = (tid & 3) * 8;
    float acc[4][4] = {};
    for (int k0 = 0; k0 < IN_DIM; k0 += 32) {
        float4 a0 = *(const float4*)&A[(t0 + lrow) * IN_DIM + k0 + lcol];
        float4 a1 = *(const float4*)&A[(t0 + lrow) * IN_DIM + k0 + lcol + 4];
        float4 b0 = *(const float4*)&B[(r0 + lrow) * IN_DIM + k0 + lcol];
        float4 b1 = *(const float4*)&B[(r0 + lrow) * IN_DIM + k0 + lcol + 4];
        __syncthreads();
        sAf[lrow][lcol + 0] = a0.x; sAf[lrow][lcol + 1] = a0.y;
        sAf[lrow][lcol + 2] = a0.z; sAf[lrow][lcol + 3] = a0.w;
        sAf[lrow][lcol + 4] = a1.x; sAf[lrow][lcol + 5] = a1.y;
        sAf[lrow][lcol + 6] = a1.z; sAf[lrow][lcol + 7] = a1.w;
        sBf[lrow][lcol + 0] = b0.x; sBf[lrow][lcol + 1] = b0.y;
        sBf[lrow][lcol + 2] = b0.z; sBf[lrow][lcol + 3] = b0.w;
        sBf[lrow][lcol + 4] = b1.x; sBf[lrow][lcol + 5] = b1.y;
        sBf[lrow][lcol + 6] = b1.z; sBf[lrow][lcol + 7] = b1.w;
        __syncthreads();
#pragma unroll
        for (int kk = 0; kk < 32; ++kk) {
            float av[4], bv[4];
#pragma unroll
            for (int i = 0; i < 4; ++i) av[i] = sAf[ty * 4 + i][kk];
#pragma unroll
            for (int j = 0; j < 4; ++j) bv[j] = sBf[tx * 4 + j][kk];
#pragma unroll
            for (int i = 0; i < 4; ++i)
#pragma unroll
                for (int j = 0; j < 4; ++j) acc[i][j] = fmaf(av[i], bv[j], acc[i][j]);
        }
    }
#pragma unroll
    for (int i = 0; i < 4; ++i)
#pragma unroll
        for (int j = 0; j < 4; ++j)
            C[(t0 + ty * 4 + i) * RES_DIM + r0 + tx * 4 + j] = acc[i][j];
}

// ---------- scan part A: warmup seeds ----------
__global__ void warmup_kernel(const float* __restrict__ U, const float* __restrict__ d,
                              float* __restrict__ sinit, int C, int W, int NC) {
    int g = blockIdx.x * blockDim.x + threadIdx.x;
    if (g >= NC * RES_DIM) return;
    int c = g >> 12;
    int r = g & (RES_DIM - 1);
    float s = 0.0f;
    if (c > 0) {
        float dr = d[r];
        const float* p = U + (size_t)(c * C - W) * RES_DIM + r;
        constexpr int PF = 8;
        float buf[PF];
#pragma unroll
        for (int i = 0; i < PF; ++i) buf[i] = p[(size_t)i * RES_DIM];
        for (int t = 0; t < W; t += PF) {
#pragma unroll
            for (int j = 0; j < PF; ++j) {
                float u = buf[j];
                int tn = t + j + PF;
                if (tn < W) buf[j] = p[(size_t)tn * RES_DIM];
                s = tanh_fast(fmaf(dr, s, u));
            }
        }
    }
    sinit[g] = s;
}

// ---------- scan part B: in-place chunked scan ----------
__global__ void scan_kernel(float* __restrict__ U, const float* __restrict__ d,
                            const float* __restrict__ sinit, int C, int NC) {
    int g = blockIdx.x * blockDim.x + threadIdx.x;
    if (g >= NC * RES_DIM) return;
    int c = g >> 12;
    int r = g & (RES_DIM - 1);
    float dr = d[r];
    float s = (c == 0) ? 0.0f : sinit[g];
    float* p = U + (size_t)c * C * RES_DIM + r;
    constexpr int PF = 8;
    float buf[PF];
#pragma unroll
    for (int i = 0; i < PF; ++i) buf[i] = p[(size_t)i * RES_DIM];
    for (int t = 0; t < C; t += PF) {
#pragma unroll
        for (int j = 0; j < PF; ++j) {
            float u = buf[j];
            int tn = t + j + PF;
            if (tn < C) buf[j] = p[(size_t)tn * RES_DIM];
            s = tanh_fast(fmaf(dr, s, u));
            p[(size_t)(t + j) * RES_DIM] = s;
        }
    }
}

// ---------- launch ----------
extern "C" void kernel_launch(void* const* d_in, const int* in_sizes, int n_in,
                              void* d_out, int out_size, void* d_ws, size_t ws_size,
                              hipStream_t stream) {
    const float* x    = (const float*)d_in[0];   // [T, 1024, 1]
    const float* W_in = (const float*)d_in[1];   // [4096, 1024]
    const float* dvec = (const float*)d_in[2];   // [4096]
    float* out = (float*)d_out;                  // [T, 4096]

    constexpr int NC   = 64;
    constexpr int CHK  = T_DIM / NC;   // 128
    constexpr int WARM = 64;

    const size_t szA = (size_t)T_DIM * 2048 * sizeof(u16);    // 32 MiB (hi+lo)
    const size_t szB = (size_t)RES_DIM * 2048 * sizeof(u16);  // 16 MiB
    const size_t szS = (size_t)NC * RES_DIM * sizeof(float);  // 1 MiB

    if (ws_size >= szA + szB + szS) {
        u16* Aop = (u16*)d_ws;
        u16* Bop = Aop + (size_t)T_DIM * 2048;
        float* sinit = (float*)(Bop + (size_t)RES_DIM * 2048);

        convert_hilo<<<2048, 256, 0, stream>>>(x, Aop, T_DIM * 128);
        convert_hilo<<<1024, 256, 0, stream>>>(W_in, Bop, RES_DIM * 128);
        gemm8<<<512, 512, 0, stream>>>(Aop, Bop, out);
        warmup_kernel<<<NC * RES_DIM / 256, 256, 0, stream>>>(out, dvec, sinit, CHK, WARM, NC);
        scan_kernel<<<NC * RES_DIM / 256, 256, 0, stream>>>(out, dvec, sinit, CHK, NC);
    } else {
        gemm_f32<<<dim3(T_DIM / 64, RES_DIM / 64), 256, 0, stream>>>(x, W_in, out);
        scan_kernel<<<RES_DIM / 256, 256, 0, stream>>>(out, dvec, nullptr, T_DIM, 1);
    }
}

// Round 3
// 299.678 us; speedup vs baseline: 1.0301x; 1.0301x over previous
//
#include <hip/hip_runtime.h>
#include <hip/hip_bf16.h>

// Problem constants
#define T_DIM 8192
#define IN_DIM 1024
#define RES_DIM 4096

typedef unsigned short u16;
typedef __bf16 bf16x8 __attribute__((ext_vector_type(8)));
typedef float f32x4 __attribute__((ext_vector_type(4)));

// ---------- helpers ----------
__device__ __forceinline__ u16 f2bf(float f) {
    unsigned u = __float_as_uint(f);
    return (u16)((u + 0x7FFFu + ((u >> 16) & 1u)) >> 16);   // RNE
}
__device__ __forceinline__ float bf2f(u16 h) {
    return __uint_as_float(((unsigned)h) << 16);
}

__device__ __forceinline__ float tanh_fast(float z) {
    z = fminf(15.0f, fmaxf(-15.0f, z));
    float e = __expf(2.0f * z);
    float inv = __builtin_amdgcn_rcpf(e + 1.0f);
    return fmaf(-2.0f, inv, 1.0f);
}

__device__ __forceinline__ void stage16(const u16* g, u16* l) {
    __builtin_amdgcn_global_load_lds(
        (const __attribute__((address_space(1))) void*)g,
        (__attribute__((address_space(3))) void*)l, 16, 0, 0);
}

// ---------- convert: f32 row-major [rows][1024] -> tiled hi(kta 0..15)/lo(16..31) bf16 ----------
// Elem index: ((((rb*32 + kta)*2 + h)*16 + fb)*64 + l)*8 + e
//   rb=row>>8, h=(row>>7)&1, mf=(row>>4)&7, l=kg*16+(row&15), k=kta_loc*64+ks*32+kg*8+e
//   A-style: fb = mf*2 + ks
//   B-style: fb = ((mf>>1)&1)*8 + (mf>>2)*4 + (mf&1)*2 + ks   (quarter nh contiguous)
__global__ void convert_hilo(const float* __restrict__ src, u16* __restrict__ dst,
                             int nchunks, int bstyle) {
    for (int g = blockIdx.x * blockDim.x + threadIdx.x; g < nchunks;
         g += gridDim.x * blockDim.x) {
        int row = g >> 7, kc = g & 127;
        int rb = row >> 8, h = (row >> 7) & 1, mf = (row >> 4) & 7, r4 = row & 15;
        int kth = kc >> 3, ks = (kc >> 2) & 1, kg = kc & 3;
        int l = kg * 16 + r4;
        int fb = bstyle ? ((((mf >> 1) & 1) << 3) | ((mf >> 2) << 2) | ((mf & 1) << 1) | ks)
                        : (mf * 2 + ks);
        const float* s = src + (size_t)row * IN_DIM + kc * 8;
        float4 f0 = *(const float4*)s;
        float4 f1 = *(const float4*)(s + 4);
        float f[8] = {f0.x, f0.y, f0.z, f0.w, f1.x, f1.y, f1.z, f1.w};
        alignas(16) u16 hv[8];
        alignas(16) u16 lv[8];
#pragma unroll
        for (int e = 0; e < 8; ++e) {
            u16 hh = f2bf(f[e]);
            hv[e] = hh;
            lv[e] = f2bf(f[e] - bf2f(hh));
        }
        size_t baseHi = ((((size_t)(rb * 32 + kth) * 2 + h) * 16 + fb) * 64 + l) * 8;
        size_t baseLo = ((((size_t)(rb * 32 + kth + 16) * 2 + h) * 16 + fb) * 64 + l) * 8;
        *(uint4*)(dst + baseHi) = *(const uint4*)hv;
        *(uint4*)(dst + baseLo) = *(const uint4*)lv;
    }
}

// ---------- 256x256 8-phase bf16 GEMM over K'=3072 (hi/lo 3-segment) ----------
// Segments: kt 0..15: Ah*Bh ; 16..31: Ah*Bl ; 32..47: Al*Bh
#define FENCE() asm volatile("" ::: "memory")
#define BAR()   do { FENCE(); __builtin_amdgcn_s_barrier(); FENCE(); } while (0)
#define WAIT6() asm volatile("s_waitcnt vmcnt(6)" ::: "memory")
#define WAIT0() asm volatile("s_waitcnt vmcnt(0)" ::: "memory")

__global__ __launch_bounds__(512, 2)
void gemm8(const u16* __restrict__ Aop, const u16* __restrict__ Bop, float* __restrict__ C) {
    __shared__ __attribute__((aligned(16))) u16 sA[2][2][8192];   // [dbuf][half][16fb*512]
    __shared__ __attribute__((aligned(16))) u16 sB[2][2][8192];

    const int tid  = threadIdx.x;
    const int lane = tid & 63;
    const int w    = tid >> 6;
    const int wr = w >> 2, wc = w & 3;

    // bijective XCD swizzle (512 blocks, 512%8==0)
    const int bid = blockIdx.x;
    const int swz = (bid & 7) * 64 + (bid >> 3);
    const int mb = swz >> 4;   // 0..31
    const int nb = swz & 15;   // 0..15

    f32x4 acc[8][4] = {};
    bf16x8 aR[4][2], bR0[2][2], bR1[2][2];

    const int wbase0 = (tid & ~63) * 8;   // wave-uniform LDS elem base (0..3584)

// Stage one A-quarter (q = mh) of tile kt into dbuf d: 2 gloads (one per half).
#define STAGE_AQ(kt, q, d) do {                                                     \
    int kta_ = ((kt) < 16) ? (kt) : ((kt) - 16);                                    \
    const u16* s_ = Aop + (size_t)(mb * 32 + kta_) * 16384 + (q) * 4096 + tid * 8;  \
    stage16(s_,        &sA[d][0][0] + (q) * 4096 + wbase0);                         \
    stage16(s_ + 8192, &sA[d][1][0] + (q) * 4096 + wbase0); } while (0)

// Stage one B-quarter (q = nh) of tile kt into dbuf d.
#define STAGE_BQ(kt, q, d) do {                                                     \
    int ktb_ = ((kt) < 32) ? (kt) : ((kt) - 32);                                    \
    const u16* s_ = Bop + (size_t)(nb * 32 + ktb_) * 16384 + (q) * 4096 + tid * 8;  \
    stage16(s_,        &sB[d][0][0] + (q) * 4096 + wbase0);                         \
    stage16(s_ + 8192, &sB[d][1][0] + (q) * 4096 + wbase0); } while (0)

#define LOAD_A(d, mh) do {                                                          \
    _Pragma("unroll") for (int i_ = 0; i_ < 4; ++i_)                                \
    _Pragma("unroll") for (int ks_ = 0; ks_ < 2; ++ks_)                             \
        aR[i_][ks_] = *(const bf16x8*)(&sA[d][wr][0] +                              \
            (((mh) * 4 + i_) * 2 + ks_) * 512 + lane * 8); } while (0)

#define LOAD_B(d, nh, BR) do {                                                      \
    _Pragma("unroll") for (int j_ = 0; j_ < 2; ++j_)                                \
    _Pragma("unroll") for (int ks_ = 0; ks_ < 2; ++ks_)                             \
        BR[j_][ks_] = *(const bf16x8*)(&sB[d][wc >> 1][0] +                         \
            ((nh) * 8 + (wc & 1) * 4 + j_ * 2 + ks_) * 512 + lane * 8); } while (0)

#define MFMA_Q(mh, nh, BR) do {                                                     \
    __builtin_amdgcn_s_setprio(1);                                                  \
    _Pragma("unroll") for (int i_ = 0; i_ < 4; ++i_)                                \
    _Pragma("unroll") for (int j_ = 0; j_ < 2; ++j_) {                              \
        acc[(mh)*4+i_][(nh)*2+j_] = __builtin_amdgcn_mfma_f32_16x16x32_bf16(        \
            aR[i_][0], BR[j_][0], acc[(mh)*4+i_][(nh)*2+j_], 0, 0, 0);              \
        acc[(mh)*4+i_][(nh)*2+j_] = __builtin_amdgcn_mfma_f32_16x16x32_bf16(        \
            aR[i_][1], BR[j_][1], acc[(mh)*4+i_][(nh)*2+j_], 0, 0, 0); }            \
    __builtin_amdgcn_s_setprio(0); } while (0)

// One iteration = 2 K-tiles (d0 = kb read p1-p4, d1 = kb+1 read p5-p8), 8 phases.
// Stage points (earliest-free placement, 3-7 phase issue->drain cover):
//   p1: B(kb+1)q0->d1   p2: A(kb+2)q0->d0   p3: B(kb+2)q1->d0   p4: A(kb+2)q1->d0
//   p5: B(kb+2)q0->d0   p6: A(kb+3)q0->d1   p7: B(kb+3)q1->d1   p8: A(kb+3)q1->d1
// Waits: end of p4 (covers d1 reads p5-p8), end of p8 (covers d0 reads next p1-p4);
// both vmcnt(6), newest drained load is 3 phases old.
#define ITER(kb, W5, W1, STG)                                                        \
    LOAD_A(0, 0); LOAD_B(0, 0, bR0); STAGE_BQ((kb)+1, 0, 1);                         \
        BAR(); MFMA_Q(0, 0, bR0); BAR();                                             \
    LOAD_B(0, 1, bR1); if (STG) STAGE_AQ((kb)+2, 0, 0);                              \
        BAR(); MFMA_Q(0, 1, bR1); BAR();                                             \
    LOAD_A(0, 1); if (STG) STAGE_BQ((kb)+2, 1, 0);                                   \
        BAR(); MFMA_Q(1, 1, bR1); BAR();                                             \
    if (STG) STAGE_AQ((kb)+2, 1, 0);                                                 \
        BAR(); MFMA_Q(1, 0, bR0); W5; BAR();                                         \
    LOAD_A(1, 0); LOAD_B(1, 0, bR0); if (STG) STAGE_BQ((kb)+2, 0, 0);                \
        BAR(); MFMA_Q(0, 0, bR0); BAR();                                             \
    LOAD_B(1, 1, bR1); if (STG) STAGE_AQ((kb)+3, 0, 1);                              \
        BAR(); MFMA_Q(0, 1, bR1); BAR();                                             \
    LOAD_A(1, 1); if (STG) STAGE_BQ((kb)+3, 1, 1);                                   \
        BAR(); MFMA_Q(1, 1, bR1); BAR();                                             \
    if (STG) STAGE_AQ((kb)+3, 1, 1);                                                 \
        BAR(); MFMA_Q(1, 0, bR0); W1; BAR();

    // Prologue: tile0 (4 quarter-points, drained at first W) then tile1 (3 points,
    // left in flight = 6 ops, drained at iter-0's p4-end wait).
    STAGE_AQ(0, 0, 0); STAGE_BQ(0, 1, 0); STAGE_AQ(0, 1, 0); STAGE_BQ(0, 0, 0);
    STAGE_AQ(1, 0, 1); STAGE_BQ(1, 1, 1); STAGE_AQ(1, 1, 1);
    WAIT6(); BAR();

    for (int it = 0; it < 23; ++it) {
        const int kb = it * 2;
        ITER(kb, WAIT6(), WAIT6(), 1);
    }
    {   // tail: kb=46; kt>=48 stages skipped; p4-end drains everything (tile 47)
        ITER(46, WAIT0(), FENCE(), 0);
    }

    // epilogue: D layout col = lane&15, row = (lane>>4)*4 + j
    const int lr = lane & 15, lq = lane >> 4;
    const size_t row0 = (size_t)mb * 256 + wr * 128;
    const size_t col0 = (size_t)nb * 256 + wc * 64;
#pragma unroll
    for (int m = 0; m < 8; ++m)
#pragma unroll
        for (int n = 0; n < 4; ++n) {
            float* cp = C + (row0 + m * 16 + lq * 4) * RES_DIM + (col0 + n * 16 + lr);
#pragma unroll
            for (int j = 0; j < 4; ++j) cp[(size_t)j * RES_DIM] = acc[m][n][j];
        }
#undef ITER
#undef MFMA_Q
#undef LOAD_B
#undef LOAD_A
#undef STAGE_BQ
#undef STAGE_AQ
}

// ---------- fallback fp32 GEMM (only if ws too small) ----------
__global__ __launch_bounds__(256)
void gemm_f32(const float* __restrict__ A, const float* __restrict__ B, float* __restrict__ C) {
    __shared__ float sAf[64][33];
    __shared__ float sBf[64][33];
    const int tid = threadIdx.x;
    const int tx = tid & 15, ty = tid >> 4;
    const size_t t0 = (size_t)blockIdx.x * 64;
    const size_t r0 = (size_t)blockIdx.y * 64;
    const int lrow = tid >> 2;
    const int lcol = (tid & 3) * 8;
    float acc[4][4] = {};
    for (int k0 = 0; k0 < IN_DIM; k0 += 32) {
        float4 a0 = *(const float4*)&A[(t0 + lrow) * IN_DIM + k0 + lcol];
        float4 a1 = *(const float4*)&A[(t0 + lrow) * IN_DIM + k0 + lcol + 4];
        float4 b0 = *(const float4*)&B[(r0 + lrow) * IN_DIM + k0 + lcol];
        float4 b1 = *(const float4*)&B[(r0 + lrow) * IN_DIM + k0 + lcol + 4];
        __syncthreads();
        sAf[lrow][lcol + 0] = a0.x; sAf[lrow][lcol + 1] = a0.y;
        sAf[lrow][lcol + 2] = a0.z; sAf[lrow][lcol + 3] = a0.w;
        sAf[lrow][lcol + 4] = a1.x; sAf[lrow][lcol + 5] = a1.y;
        sAf[lrow][lcol + 6] = a1.z; sAf[lrow][lcol + 7] = a1.w;
        sBf[lrow][lcol + 0] = b0.x; sBf[lrow][lcol + 1] = b0.y;
        sBf[lrow][lcol + 2] = b0.z; sBf[lrow][lcol + 3] = b0.w;
        sBf[lrow][lcol + 4] = b1.x; sBf[lrow][lcol + 5] = b1.y;
        sBf[lrow][lcol + 6] = b1.z; sBf[lrow][lcol + 7] = b1.w;
        __syncthreads();
#pragma unroll
        for (int kk = 0; kk < 32; ++kk) {
            float av[4], bv[4];
#pragma unroll
            for (int i = 0; i < 4; ++i) av[i] = sAf[ty * 4 + i][kk];
#pragma unroll
            for (int j = 0; j < 4; ++j) bv[j] = sBf[tx * 4 + j][kk];
#pragma unroll
            for (int i = 0; i < 4; ++i)
#pragma unroll
                for (int j = 0; j < 4; ++j) acc[i][j] = fmaf(av[i], bv[j], acc[i][j]);
        }
    }
#pragma unroll
    for (int i = 0; i < 4; ++i)
#pragma unroll
        for (int j = 0; j < 4; ++j)
            C[(t0 + ty * 4 + i) * RES_DIM + r0 + tx * 4 + j] = acc[i][j];
}

// ---------- scan part A: warmup seeds ----------
__global__ void warmup_kernel(const float* __restrict__ U, const float* __restrict__ d,
                              float* __restrict__ sinit, int C, int W, int NC) {
    int g = blockIdx.x * blockDim.x + threadIdx.x;
    if (g >= NC * RES_DIM) return;
    int c = g >> 12;
    int r = g & (RES_DIM - 1);
    float s = 0.0f;
    if (c > 0) {
        float dr = d[r];
        const float* p = U + (size_t)(c * C - W) * RES_DIM + r;
        constexpr int PF = 8;
        float buf[PF];
#pragma unroll
        for (int i = 0; i < PF; ++i) buf[i] = p[(size_t)i * RES_DIM];
        for (int t = 0; t < W; t += PF) {
#pragma unroll
            for (int j = 0; j < PF; ++j) {
                float u = buf[j];
                int tn = t + j + PF;
                if (tn < W) buf[j] = p[(size_t)tn * RES_DIM];
                s = tanh_fast(fmaf(dr, s, u));
            }
        }
    }
    sinit[g] = s;
}

// ---------- scan part B: in-place chunked scan ----------
__global__ void scan_kernel(float* __restrict__ U, const float* __restrict__ d,
                            const float* __restrict__ sinit, int C, int NC) {
    int g = blockIdx.x * blockDim.x + threadIdx.x;
    if (g >= NC * RES_DIM) return;
    int c = g >> 12;
    int r = g & (RES_DIM - 1);
    float dr = d[r];
    float s = (c == 0) ? 0.0f : sinit[g];
    float* p = U + (size_t)c * C * RES_DIM + r;
    constexpr int PF = 8;
    float buf[PF];
#pragma unroll
    for (int i = 0; i < PF; ++i) buf[i] = p[(size_t)i * RES_DIM];
    for (int t = 0; t < C; t += PF) {
#pragma unroll
        for (int j = 0; j < PF; ++j) {
            float u = buf[j];
            int tn = t + j + PF;
            if (tn < C) buf[j] = p[(size_t)tn * RES_DIM];
            s = tanh_fast(fmaf(dr, s, u));
            p[(size_t)(t + j) * RES_DIM] = s;
        }
    }
}

// ---------- launch ----------
extern "C" void kernel_launch(void* const* d_in, const int* in_sizes, int n_in,
                              void* d_out, int out_size, void* d_ws, size_t ws_size,
                              hipStream_t stream) {
    const float* x    = (const float*)d_in[0];   // [T, 1024, 1]
    const float* W_in = (const float*)d_in[1];   // [4096, 1024]
    const float* dvec = (const float*)d_in[2];   // [4096]
    float* out = (float*)d_out;                  // [T, 4096]

    constexpr int NC   = 64;
    constexpr int CHK  = T_DIM / NC;   // 128
    constexpr int WARM = 64;

    const size_t szA = (size_t)T_DIM * 2048 * sizeof(u16);    // 32 MiB (hi+lo)
    const size_t szB = (size_t)RES_DIM * 2048 * sizeof(u16);  // 16 MiB
    const size_t szS = (size_t)NC * RES_DIM * sizeof(float);  // 1 MiB

    if (ws_size >= szA + szB + szS) {
        u16* Aop = (u16*)d_ws;
        u16* Bop = Aop + (size_t)T_DIM * 2048;
        float* sinit = (float*)(Bop + (size_t)RES_DIM * 2048);

        convert_hilo<<<2048, 256, 0, stream>>>(x, Aop, T_DIM * 128, 0);
        convert_hilo<<<1024, 256, 0, stream>>>(W_in, Bop, RES_DIM * 128, 1);
        gemm8<<<512, 512, 0, stream>>>(Aop, Bop, out);
        warmup_kernel<<<NC * RES_DIM / 256, 256, 0, stream>>>(out, dvec, sinit, CHK, WARM, NC);
        scan_kernel<<<NC * RES_DIM / 256, 256, 0, stream>>>(out, dvec, sinit, CHK, NC);
    } else {
        gemm_f32<<<dim3(T_DIM / 64, RES_DIM / 64), 256, 0, stream>>>(x, W_in, out);
        scan_kernel<<<RES_DIM / 256, 256, 0, stream>>>(out, dvec, nullptr, T_DIM, 1);
    }
}